// Round 5
// baseline (701.316 us; speedup 1.0000x reference)
//
#include <hip/hip_runtime.h>
#include <hip/hip_bf16.h>
#include <math.h>

// Problem constants (from reference): B=2, T=4096, N=8, D=2048, EPS=1e-6, TEMP=1
#define NROWS 8
#define DIM   2048
#define EPSV  1e-6f
#define NTHREADS 512
#define NWAVES   (NTHREADS / 64)

// One block of 512 threads per (b,t) position.
// Each thread owns 4 d-elements (one float4: d = tid*4) of ALL 8 rows
// -> 32 VGPRs of row payload. Single pass over HBM, no spill risk.
__global__ __launch_bounds__(NTHREADS) void block_attn_route(
    const float* __restrict__ src,      // [BT, NROWS, DIM]
    const float* __restrict__ w_query,  // [DIM]
    const float* __restrict__ norm_w,   // [DIM]
    float* __restrict__ out)            // [BT, DIM]
{
    const int bt  = blockIdx.x;
    const int tid = threadIdx.x;
    const int d   = tid * 4;          // 0..2047, 512 threads x 4 floats = 2048

    const float* base = src + (size_t)bt * (NROWS * DIM);

    // effective query = w_query * norm_weight (broadcast loads, L2-resident)
    float4 wq = *(const float4*)(w_query + d);
    float4 nw = *(const float4*)(norm_w + d);
    float4 q;
    q.x = wq.x * nw.x; q.y = wq.y * nw.y; q.z = wq.z * nw.z; q.w = wq.w * nw.w;

    // Load all 8 rows' chunks first (16B coalesced, 8 outstanding loads/thread)
    float4 s[NROWS];
    #pragma unroll
    for (int n = 0; n < NROWS; ++n) {
        s[n] = *(const float4*)(base + n * DIM + d);
    }

    float sumsq[NROWS], dotq[NROWS];
    #pragma unroll
    for (int n = 0; n < NROWS; ++n) {
        sumsq[n] = s[n].x * s[n].x + s[n].y * s[n].y
                 + s[n].z * s[n].z + s[n].w * s[n].w;
        dotq[n]  = s[n].x * q.x + s[n].y * q.y
                 + s[n].z * q.z + s[n].w * q.w;
    }

    // Wave-level butterfly reduction of 16 partials (8 rows x {sumsq, dot}).
    #pragma unroll
    for (int n = 0; n < NROWS; ++n) {
        #pragma unroll
        for (int off = 32; off >= 1; off >>= 1) {
            sumsq[n] += __shfl_xor(sumsq[n], off, 64);
            dotq[n]  += __shfl_xor(dotq[n],  off, 64);
        }
    }

    // Cross-wave combine via tiny LDS buffer: [16 values][8 waves]
    __shared__ float red[2 * NROWS][NWAVES];
    const int wave = tid >> 6;
    const int lane = tid & 63;
    if (lane == 0) {
        #pragma unroll
        for (int n = 0; n < NROWS; ++n) {
            red[n][wave]         = sumsq[n];
            red[n + NROWS][wave] = dotq[n];
        }
    }
    __syncthreads();

    // Every thread redundantly computes the 8 scores + softmax (broadcast LDS reads).
    const float inv_d      = 1.0f / (float)DIM;
    const float inv_sqrt_d = 0.022097086912079608f;  // 1/sqrt(2048)
    float scores[NROWS];
    #pragma unroll
    for (int n = 0; n < NROWS; ++n) {
        float ss = 0.f, dt = 0.f;
        #pragma unroll
        for (int wv = 0; wv < NWAVES; ++wv) {
            ss += red[n][wv];
            dt += red[n + NROWS][wv];
        }
        float inv_rms = rsqrtf(ss * inv_d + EPSV);
        scores[n] = dt * inv_rms * inv_sqrt_d;
    }

    float m = scores[0];
    #pragma unroll
    for (int n = 1; n < NROWS; ++n) m = fmaxf(m, scores[n]);
    float w[NROWS];
    float wsum = 0.0f;
    #pragma unroll
    for (int n = 0; n < NROWS; ++n) {
        w[n] = __expf(scores[n] - m);
        wsum += w[n];
    }
    const float inv_wsum = 1.0f / wsum;

    // Thread-local weighted combine of the register-resident rows.
    float4 o = make_float4(0.f, 0.f, 0.f, 0.f);
    #pragma unroll
    for (int n = 0; n < NROWS; ++n) {
        const float wn = w[n] * inv_wsum;
        o.x += wn * s[n].x; o.y += wn * s[n].y;
        o.z += wn * s[n].z; o.w += wn * s[n].w;
    }

    float* op = out + (size_t)bt * DIM;
    *(float4*)(op + d) = o;
}

extern "C" void kernel_launch(void* const* d_in, const int* in_sizes, int n_in,
                              void* d_out, int out_size, void* d_ws, size_t ws_size,
                              hipStream_t stream) {
    const float* src = (const float*)d_in[0];   // [B,T,N,D] fp32
    const float* wq  = (const float*)d_in[1];   // [D]
    const float* nw  = (const float*)d_in[2];   // [D]
    float* out       = (float*)d_out;           // [B,T,D] fp32

    const int bt = in_sizes[0] / (NROWS * DIM); // B*T = 8192
    block_attn_route<<<bt, NTHREADS, 0, stream>>>(src, wq, nw, out);
}